// Round 5
// baseline (7442.091 us; speedup 1.0000x reference)
//
#include <hip/hip_runtime.h>
#include <hip/hip_fp16.h>
#include <math.h>

#define B_ 128
#define N_ 128
#define T_ 256
#define H_ 256
#define D_ 50

// tree GEMV: K rows padded to 576 = 72 u-chunks of 8: [c 0..255 | h 256..511 | th 512..561 | pad..575]
// layout PWK[u*1024 + C]  (uint4 = 8 f16 K-values for global column C) -> wave-coalesced 1KB loads
// tracking: K padded to 840 = 5 slices x 168 rows (21 u-chunks of 8):
//   [bt_h 0..255 | h1 256..511 | h2 512..767 | th 768..817 | pad..839]
// layout WTK[u*1000 + d*5 + ks] ; per-thread slice = 21 uint4, first 12 held in registers
#define TREE_U 72
#define TRK_U  21
#define TRK_REGU 12

// ---- workspace layout (float element offsets) ----
#define OFF_SH   0u             // stack_h: B*(T+1)*H = 8421376
#define OFF_SC   8421376u       // stack_c: 8421376
#define OFF_PWK  16842752u      // tree weights: 73728 uint4 = 294912 floats
#define OFF_WTK  17137664u      // tracking weights: 21000 uint4 = 84000 floats
#define OFF_BCOL 17221664u      // 1024
#define OFF_BTRK 17222688u      // 200
#define OFF_FLAG 17222888u      // int x B*T*2 = 65536
#define OFF_IDX  17288424u      // int x B*T*3 = 98304
// end 17386728 floats (~66.3 MiB)

typedef _Float16 half2v __attribute__((ext_vector_type(2)));

__device__ __forceinline__ float sigf(float x) { return 1.0f / (1.0f + expf(-x)); }

__device__ __forceinline__ unsigned packh2(float a, float b) {
    half2v h = { (_Float16)a, (_Float16)b };
    return __builtin_bit_cast(unsigned, h);
}

__device__ __forceinline__ float dot2(unsigned wu, unsigned vu, float acc) {
#if __has_builtin(__builtin_amdgcn_fdot2)
    return __builtin_amdgcn_fdot2(__builtin_bit_cast(half2v, wu),
                                  __builtin_bit_cast(half2v, vu), acc, false);
#else
    half2v w = __builtin_bit_cast(half2v, wu), v = __builtin_bit_cast(half2v, vu);
    return fmaf((float)w.x, (float)v.x, fmaf((float)w.y, (float)v.y, acc));
#endif
}

__device__ __forceinline__ float aload(const float* p) {
    int v = __hip_atomic_load((const int*)p, __ATOMIC_RELAXED, __HIP_MEMORY_SCOPE_AGENT);
    return __int_as_float(v);
}
__device__ __forceinline__ void astore(float* p, float x) {
    __hip_atomic_store((int*)p, __float_as_int(x), __ATOMIC_RELAXED, __HIP_MEMORY_SCOPE_AGENT);
}

// ------------------------------------------------------------------
// queue/bptr trajectory depends only on transitions: precompute sp1/sp2/bp
// ------------------------------------------------------------------
__global__ void sim_idx(const int* __restrict__ trans, int* __restrict__ idx) {
    int b = blockIdx.x * blockDim.x + threadIdx.x;
    if (b >= B_) return;
    int queue[T_ + 1];
    int qlen = 0, bptr = 0;
    for (int st = 0; st < T_; ++st) {
        int tr = trans[b * T_ + st];
        int mask = (tr >= 1);
        int sp1 = (qlen >= 1) ? queue[qlen - 1] : 0;
        int sp2 = (qlen >= 2) ? queue[qlen - 2] : 0;
        int bp = bptr < (N_ - 1) ? bptr : (N_ - 1);
        int o = (b * T_ + st) * 3;
        idx[o] = sp1; idx[o + 1] = sp2; idx[o + 2] = bp;
        int qlen2 = mask ? (qlen - 2 > 0 ? qlen - 2 : 0) : qlen;
        queue[qlen2] = st + 1;
        qlen = qlen2 + 1;
        bptr += mask ? 0 : 1;
    }
}

// ------------------------------------------------------------------
// Tree weights -> PWK[u*1024 + C], uint4 = f16 K-rows 8u..8u+7 of column C.
// C = 4*j + g; g: 0=i(Ul0,Wx0,b0) 1=o(Ul2,Wx2,b2) 2=f(Ul1,Wx2!,b1) 3=u(Ul3,Wx3,b3)
// rows r: <256 Ul (c-operand), <512 Ur (h-operand), <562 Wx (th), else 0
// ------------------------------------------------------------------
__global__ void pack_tree(const float* __restrict__ Ul, const float* __restrict__ Ur,
                          const float* __restrict__ Wx, uint4* __restrict__ PW) {
    int i = blockIdx.x * blockDim.x + threadIdx.x;
    if (i >= TREE_U * 1024) return;
    int u = i >> 10, C = i & 1023, j = C >> 2, g = C & 3;
    const int gl[4] = {0, 2, 1, 3};
    const int gx[4] = {0, 2, 2, 3};
    float f[8];
    for (int kk = 0; kk < 8; ++kk) {
        int r = u * 8 + kk;
        if (r < 256)      f[kk] = Ul[(gl[g] * H_ + j) * H_ + r];
        else if (r < 512) f[kk] = Ur[(gl[g] * H_ + j) * H_ + (r - 256)];
        else if (r < 562) f[kk] = Wx[(gx[g] * H_ + j) * D_ + (r - 512)];
        else              f[kk] = 0.0f;
    }
    PW[i] = make_uint4(packh2(f[0], f[1]), packh2(f[2], f[3]),
                       packh2(f[4], f[5]), packh2(f[6], f[7]));
}

// Tracking weights -> WTK[u*1000 + d*5 + ks], uint4 = f16 K-rows ks*168+8u .. +7 of dim d.
__global__ void pack_trk(const float* __restrict__ Wih, const float* __restrict__ Whh,
                         uint4* __restrict__ WT) {
    int i = blockIdx.x * blockDim.x + threadIdx.x;
    if (i >= TRK_U * 1000) return;
    int u = i / 1000, rem = i % 1000, d = rem / 5, ks = rem % 5;
    float f[8];
    for (int kk = 0; kk < 8; ++kk) {
        int r = ks * 168 + u * 8 + kk;
        if (r < 768)      f[kk] = Wih[d * 768 + r];
        else if (r < 818) f[kk] = Whh[d * 50 + (r - 768)];
        else              f[kk] = 0.0f;
    }
    WT[i] = make_uint4(packh2(f[0], f[1]), packh2(f[2], f[3]),
                       packh2(f[4], f[5]), packh2(f[6], f[7]));
}

__global__ void pack_bias(const float* __restrict__ bias4, const float* __restrict__ bih,
                          const float* __restrict__ bhh,
                          float* __restrict__ bcol, float* __restrict__ btrk) {
    int i = blockIdx.x * blockDim.x + threadIdx.x;
    if (i < 1024) {
        int j = i >> 2, g = i & 3;
        const int gb[4] = {0, 2, 1, 3};
        bcol[i] = bias4[gb[g] * H_ + j];
    } else if (i < 1224) {
        int d = i - 1024;
        btrk[d] = bih[d] + bhh[d];
    }
}

// zero flags + stack row 0 (ws is re-poisoned 0xAA before every timed launch)
__global__ void init_zero(float* __restrict__ ws) {
    int i = blockIdx.x * blockDim.x + threadIdx.x;
    if (i < B_ * T_ * 2) ((int*)(ws + OFF_FLAG))[i] = 0;
    if (i < B_ * H_) {
        int b = i >> 8, j = i & 255;
        ws[OFF_SH + (size_t)b * (T_ + 1) * H_ + j] = 0.0f;
        ws[OFF_SC + (size_t)b * (T_ + 1) * H_ + j] = 0.0f;
    }
}

// batched tree dot: issue S coalesced uint4 loads, then consume (8 dot2 each)
template <int S>
__device__ __forceinline__ void tree_batch(const uint4* __restrict__ wpk, int u0,
                                           const unsigned* __restrict__ q1,
                                           const unsigned* __restrict__ q2,
                                           float& a1, float& a2) {
    uint4 wb[S];
#pragma unroll
    for (int i = 0; i < S; ++i) wb[i] = wpk[(size_t)(u0 + i) << 10];
#pragma unroll
    for (int i = 0; i < S; ++i) {
        const int u = u0 + i;
        const uint4 v1 = *(const uint4*)(q1 + u * 4);
        const uint4 v2 = *(const uint4*)(q2 + u * 4);
        a1 = dot2(wb[i].x, v1.x, a1); a1 = dot2(wb[i].y, v1.y, a1);
        a1 = dot2(wb[i].z, v1.z, a1); a1 = dot2(wb[i].w, v1.w, a1);
        a2 = dot2(wb[i].x, v2.x, a2); a2 = dot2(wb[i].y, v2.y, a2);
        a2 = dot2(wb[i].z, v2.z, a2); a2 = dot2(wb[i].w, v2.w, a2);
    }
}

// ------------------------------------------------------------------
// Main: 256 WGs = 2 per batch element (column-split pair), 1024 threads.
// __launch_bounds__(1024, 4): block = 16 waves = 4 waves/EU -> VGPR cap 128.
// Round-2 regression root cause: bare __launch_bounds__(1024) let the
// compiler target 2 blocks/CU (64 VGPRs) and spill twr[12] (48 VGPRs) to
// scratch -> 13 GB/dispatch of scratch HBM traffic. VGPR must read >64.
// ------------------------------------------------------------------
__global__ __launch_bounds__(1024, 4)
void trnn_main(const float* __restrict__ tokens_h, const float* __restrict__ tokens_c,
               const int* __restrict__ trans,
               const float* __restrict__ th0, const float* __restrict__ tc0,
               float* __restrict__ ws, const int* __restrict__ idx,
               float* __restrict__ out) {
    const int b   = blockIdx.x & 127;
    const int hw  = blockIdx.x >> 7;
    const int tid = threadIdx.x;

    float* stack_h = ws + OFF_SH + (size_t)b * (T_ + 1) * H_;
    float* stack_c = ws + OFF_SC + (size_t)b * (T_ + 1) * H_;
    const uint4* PWK4 = (const uint4*)(ws + OFF_PWK);
    const uint4* WTK4 = (const uint4*)(ws + OFF_WTK);
    const float* bcol = ws + OFF_BCOL;
    const float* btrk = ws + OFF_BTRK;
    int* flags = (int*)(ws + OFF_FLAG);

    __shared__ __align__(16) unsigned av1[288], av2[288];  // half2: [c|h|th|pad]
    __shared__ __align__(16) unsigned tav[420];            // half2: [bt_h|h1|h2|th|pad]
    __shared__ float h1s[256], h2s[256], c2s[256], bths[256], btcs[256];
    __shared__ float tc_l[50];
    __shared__ float ptrk[5][200];
    __shared__ float ptree[2][2][512];
    __shared__ float act[2][512];

    // tracking-thread invariants
    const int td  = tid / 5;     // output dim (0..199) for tid<1000
    const int tks = tid % 5;     // K-slice
    const bool trkA = tid < 1000;

    // register-resident tracking weights (loaded once; constant across steps)
    uint4 twr[TRK_REGU];
    if (trkA) {
#pragma unroll
        for (int u = 0; u < TRK_REGU; ++u) twr[u] = WTK4[u * 1000 + tid];
    }

    // tree invariants: thread = (col 0..511, khalf)
    const int col = tid & 511;
    const int kh  = tid >> 9;
    const uint4* wpk = PWK4 + (hw * 512 + col);
    const float bias_c = bcol[hw * 512 + col];

    // ---- init ----
    if (tid < 25) {
        float x = th0[b * D_ + 2 * tid], y = th0[b * D_ + 2 * tid + 1];
        unsigned p = packh2(x, y);
        av1[256 + tid] = p; av2[256 + tid] = p; tav[384 + tid] = p;
    }
    if (tid < 50) tc_l[tid] = tc0[b * D_ + tid];
    if (tid >= 281 && tid < 288) { av1[tid] = 0u; av2[tid] = 0u; }
    if (tid < 11) tav[409 + tid] = 0u;
    __syncthreads();

    for (int t = 1; t <= T_; ++t) {
        const int st = t - 1;
        const int i3 = (b * T_ + st) * 3;
        const int sp1 = idx[i3], sp2 = idx[i3 + 1], bp = idx[i3 + 2];

        // ---- P0: wait for partner's row t-1 ----
        if (t >= 2) {
            if (tid == 0) {
                int* f = &flags[(b * T_ + (t - 1)) * 2 + (hw ^ 1)];
                while (__hip_atomic_load(f, __ATOMIC_RELAXED, __HIP_MEMORY_SCOPE_AGENT) == 0)
                    __builtin_amdgcn_s_sleep(1);
            }
            __syncthreads();
        }

        // ---- P1: gather rows, convert to half2, keep f32 where combine needs ----
        {
            const int g = tid >> 7, t2 = tid & 127;
            const int e0 = 2 * t2, e1 = e0 + 1;
            if (g == 0) {
                float x = aload(&stack_c[sp1 * H_ + e0]), y = aload(&stack_c[sp1 * H_ + e1]);
                av1[t2] = packh2(x, y);
            } else if (g == 1) {
                float x = aload(&stack_h[sp1 * H_ + e0]), y = aload(&stack_h[sp1 * H_ + e1]);
                unsigned p = packh2(x, y);
                av1[128 + t2] = p; tav[128 + t2] = p; h1s[e0] = x; h1s[e1] = y;
            } else if (g == 2) {
                float x = aload(&stack_c[sp2 * H_ + e0]), y = aload(&stack_c[sp2 * H_ + e1]);
                av2[t2] = packh2(x, y); c2s[e0] = x; c2s[e1] = y;
            } else if (g == 3) {
                float x = aload(&stack_h[sp2 * H_ + e0]), y = aload(&stack_h[sp2 * H_ + e1]);
                unsigned p = packh2(x, y);
                av2[128 + t2] = p; tav[256 + t2] = p; h2s[e0] = x; h2s[e1] = y;
            } else if (g == 4) {
                const float* src = tokens_h + ((size_t)b * N_ + bp) * H_;
                float x = src[e0], y = src[e1];
                tav[t2] = packh2(x, y); bths[e0] = x; bths[e1] = y;
            } else if (g == 5) {
                const float* src = tokens_c + ((size_t)b * N_ + bp) * H_;
                btcs[e0] = src[e0]; btcs[e1] = src[e1];
            }
        }
        __syncthreads();

        // ---- P2: tracking partials (12 reg-held + 9 streamed uint4 per thread) ----
        if (trkA) {
            const unsigned* tv = tav + tks * 84;
            uint4 sb[TRK_U - TRK_REGU];
#pragma unroll
            for (int i = 0; i < TRK_U - TRK_REGU; ++i)
                sb[i] = WTK4[(TRK_REGU + i) * 1000 + tid];
            float a = 0.f;
#pragma unroll
            for (int u = 0; u < TRK_REGU; ++u) {
                const uint4 v = *(const uint4*)(tv + u * 4);
                a = dot2(twr[u].x, v.x, a); a = dot2(twr[u].y, v.y, a);
                a = dot2(twr[u].z, v.z, a); a = dot2(twr[u].w, v.w, a);
            }
#pragma unroll
            for (int i = 0; i < TRK_U - TRK_REGU; ++i) {
                const uint4 v = *(const uint4*)(tv + (TRK_REGU + i) * 4);
                a = dot2(sb[i].x, v.x, a); a = dot2(sb[i].y, v.y, a);
                a = dot2(sb[i].z, v.z, a); a = dot2(sb[i].w, v.w, a);
            }
            ptrk[tks][td] = a;
        }
        __syncthreads();

        // ---- P3 (threads 0..24): th/tc update; others fall straight into tree ----
        if (tid < 25) {
            float thv0 = 0.f, thv1 = 0.f;
#pragma unroll
            for (int q = 0; q < 2; ++q) {
                const int d = 2 * tid + q;
                float gi = btrk[d], gf = btrk[50 + d], gg = btrk[100 + d], go = btrk[150 + d];
#pragma unroll
                for (int ks = 0; ks < 5; ++ks) {
                    gi += ptrk[ks][d]; gf += ptrk[ks][50 + d];
                    gg += ptrk[ks][100 + d]; go += ptrk[ks][150 + d];
                }
                float c = fmaf(sigf(gf), tc_l[d], sigf(gi) * tanhf(gg));
                tc_l[d] = c;
                float thv = sigf(go) * tanhf(c);
                if (q == 0) thv0 = thv; else thv1 = thv;
            }
            unsigned p = packh2(thv0, thv1);
            av1[256 + tid] = p; av2[256 + tid] = p; tav[384 + tid] = p;
        }

        // ---- tree main (rows 0..511: no th dependency; overlaps P3) ----
        float a1 = 0.f, a2 = 0.f;
        if (kh == 0) {
            tree_batch<6>(wpk, 0,  av1, av2, a1, a2);
            tree_batch<6>(wpk, 6,  av1, av2, a1, a2);
            tree_batch<6>(wpk, 12, av1, av2, a1, a2);
            tree_batch<6>(wpk, 18, av1, av2, a1, a2);
            tree_batch<6>(wpk, 24, av1, av2, a1, a2);
            tree_batch<6>(wpk, 30, av1, av2, a1, a2);
            ptree[0][0][col] = a1; ptree[1][0][col] = a2;
        } else {
            tree_batch<7>(wpk, 36, av1, av2, a1, a2);
            tree_batch<7>(wpk, 43, av1, av2, a1, a2);
            tree_batch<7>(wpk, 50, av1, av2, a1, a2);
            tree_batch<7>(wpk, 57, av1, av2, a1, a2);
        }
        __syncthreads();   // th (P3) now visible

        // ---- tree tail (rows 512..575: th block) ----
        if (kh == 1) {
            tree_batch<4>(wpk, 64, av1, av2, a1, a2);
            tree_batch<4>(wpk, 68, av1, av2, a1, a2);
            ptree[0][1][col] = a1; ptree[1][1][col] = a2;
        }
        __syncthreads();

        // ---- P5: reduce + nonlinearity (thread = (call, col)) ----
        {
            const int call = tid >> 9, c = tid & 511;
            float s = bias_c + ptree[call][0][c] + ptree[call][1][c];
            act[call][c] = ((c & 3) == 3) ? tanhf(s) : sigf(s);
        }
        __syncthreads();

        // ---- P6: combine + stack write (our 128 of 256 output rows) ----
        if (tid < 128) {
            const int jl = tid, j = hw * 128 + jl;
            const int c0 = 4 * jl;
            const float i1 = act[0][c0], o1 = act[0][c0 + 1], f1 = act[0][c0 + 2], u1 = act[0][c0 + 3];
            const float i2 = act[1][c0], o2 = act[1][c0 + 1], f2 = act[1][c0 + 2], u2 = act[1][c0 + 3];
            // faithful to source: cc1 = i*u + f*(c2+h2); cc2 = i*u + f*(c2+h1)
            const float cc1 = fmaf(i1, u1, f1 * (c2s[j] + h2s[j]));
            const float cc2 = fmaf(i2, u2, f2 * (c2s[j] + h1s[j]));
            const float hh1 = o1 * tanhf(cc1);
            const float hh2 = o2 * tanhf(cc2);
            const int tr = trans[b * T_ + st];
            float nh, nc;
            if (tr == 0)      { nh = bths[j]; nc = btcs[j]; }
            else if (tr == 1) { nh = hh1; nc = cc1; }
            else              { nh = hh2; nc = cc2; }
            astore(&stack_h[t * H_ + j], nh);
            astore(&stack_c[t * H_ + j], nc);
            if (t == T_) out[b * H_ + j] = nh;
        }
        asm volatile("s_waitcnt vmcnt(0)" ::: "memory");
        __syncthreads();
        if (tid == 0 && t < T_) {
            __hip_atomic_store(&flags[(b * T_ + t) * 2 + hw], 1,
                               __ATOMIC_RELEASE, __HIP_MEMORY_SCOPE_AGENT);
        }
    }
}

extern "C" void kernel_launch(void* const* d_in, const int* in_sizes, int n_in,
                              void* d_out, int out_size, void* d_ws, size_t ws_size,
                              hipStream_t stream) {
    (void)in_sizes; (void)n_in; (void)out_size; (void)ws_size;
    const float* tokens_h = (const float*)d_in[0];
    const float* tokens_c = (const float*)d_in[1];
    const int*   trans    = (const int*)d_in[2];
    const float* th0      = (const float*)d_in[3];
    const float* tc0      = (const float*)d_in[4];
    const float* Wx       = (const float*)d_in[5];
    const float* Ul       = (const float*)d_in[6];
    const float* Ur       = (const float*)d_in[7];
    const float* bias4    = (const float*)d_in[8];
    const float* Wih      = (const float*)d_in[9];
    const float* Whh      = (const float*)d_in[10];
    const float* bih      = (const float*)d_in[11];
    const float* bhh      = (const float*)d_in[12];

    float* ws = (float*)d_ws;
    uint4* PWK  = (uint4*)(ws + OFF_PWK);
    uint4* WTK  = (uint4*)(ws + OFF_WTK);
    float* bcol = ws + OFF_BCOL;
    float* btrk = ws + OFF_BTRK;
    int*   idx  = (int*)(ws + OFF_IDX);

    hipLaunchKernelGGL(init_zero, dim3(256), dim3(256), 0, stream, ws);
    hipLaunchKernelGGL(sim_idx, dim3(1), dim3(128), 0, stream, trans, idx);
    hipLaunchKernelGGL(pack_tree, dim3((TREE_U * 1024 + 255) / 256), dim3(256), 0, stream,
                       Ul, Ur, Wx, PWK);
    hipLaunchKernelGGL(pack_trk, dim3((TRK_U * 1000 + 255) / 256), dim3(256), 0, stream,
                       Wih, Whh, WTK);
    hipLaunchKernelGGL(pack_bias, dim3(5), dim3(256), 0, stream, bias4, bih, bhh, bcol, btrk);
    hipLaunchKernelGGL(trnn_main, dim3(256), dim3(1024), 0, stream,
                       tokens_h, tokens_c, trans, th0, tc0, ws, idx, (float*)d_out);
}

// Round 6
// 6453.725 us; speedup vs baseline: 1.1531x; 1.1531x over previous
//
#include <hip/hip_runtime.h>
#include <hip/hip_fp16.h>
#include <math.h>

#define B_ 128
#define N_ 128
#define T_ 256
#define H_ 256
#define D_ 50

// tree GEMV: K rows padded to 576 = 72 u-chunks of 8: [c 0..255 | h 256..511 | th 512..561 | pad..575]
// layout PWK[u*1024 + C]  (uint4 = 8 f16 K-values for global column C) -> wave-coalesced 1KB loads
// tracking: K padded to 840 = 5 slices x 168 rows (21 u-chunks of 8):
//   [bt_h 0..255 | h1 256..511 | h2 512..767 | th 768..817 | pad..839]
// layout WTK[u*1000 + d*5 + ks] ; per-thread slice = 21 uint4, streamed 7-at-a-time
// (NO register residency: at 1024-thread blocks the compiler pins VGPR=64 and
//  spills any persistent array -> 12.6 GB/dispatch scratch re-reads, measured r3/r5)
#define TREE_U 72
#define TRK_U  21

// ---- workspace layout (float element offsets) ----
#define OFF_SH   0u             // stack_h: B*(T+1)*H = 8421376
#define OFF_SC   8421376u       // stack_c: 8421376
#define OFF_PWK  16842752u      // tree weights: 73728 uint4 = 294912 floats
#define OFF_WTK  17137664u      // tracking weights: 21000 uint4 = 84000 floats
#define OFF_BCOL 17221664u      // 1024
#define OFF_BTRK 17222688u      // 200
#define OFF_FLAG 17222888u      // int x B*T*2 = 65536
#define OFF_IDX  17288424u      // int x B*T*3 = 98304
// end 17386728 floats (~66.3 MiB)

typedef _Float16 half2v __attribute__((ext_vector_type(2)));

__device__ __forceinline__ float sigf(float x) { return 1.0f / (1.0f + expf(-x)); }

__device__ __forceinline__ unsigned packh2(float a, float b) {
    half2v h = { (_Float16)a, (_Float16)b };
    return __builtin_bit_cast(unsigned, h);
}

__device__ __forceinline__ float dot2(unsigned wu, unsigned vu, float acc) {
#if __has_builtin(__builtin_amdgcn_fdot2)
    return __builtin_amdgcn_fdot2(__builtin_bit_cast(half2v, wu),
                                  __builtin_bit_cast(half2v, vu), acc, false);
#else
    half2v w = __builtin_bit_cast(half2v, wu), v = __builtin_bit_cast(half2v, vu);
    return fmaf((float)w.x, (float)v.x, fmaf((float)w.y, (float)v.y, acc));
#endif
}

__device__ __forceinline__ float aload(const float* p) {
    int v = __hip_atomic_load((const int*)p, __ATOMIC_RELAXED, __HIP_MEMORY_SCOPE_AGENT);
    return __int_as_float(v);
}
__device__ __forceinline__ void astore(float* p, float x) {
    __hip_atomic_store((int*)p, __float_as_int(x), __ATOMIC_RELAXED, __HIP_MEMORY_SCOPE_AGENT);
}

// ------------------------------------------------------------------
// queue/bptr trajectory depends only on transitions: precompute sp1/sp2/bp
// ------------------------------------------------------------------
__global__ void sim_idx(const int* __restrict__ trans, int* __restrict__ idx) {
    int b = blockIdx.x * blockDim.x + threadIdx.x;
    if (b >= B_) return;
    int queue[T_ + 1];
    int qlen = 0, bptr = 0;
    for (int st = 0; st < T_; ++st) {
        int tr = trans[b * T_ + st];
        int mask = (tr >= 1);
        int sp1 = (qlen >= 1) ? queue[qlen - 1] : 0;
        int sp2 = (qlen >= 2) ? queue[qlen - 2] : 0;
        int bp = bptr < (N_ - 1) ? bptr : (N_ - 1);
        int o = (b * T_ + st) * 3;
        idx[o] = sp1; idx[o + 1] = sp2; idx[o + 2] = bp;
        int qlen2 = mask ? (qlen - 2 > 0 ? qlen - 2 : 0) : qlen;
        queue[qlen2] = st + 1;
        qlen = qlen2 + 1;
        bptr += mask ? 0 : 1;
    }
}

// ------------------------------------------------------------------
// Tree weights -> PWK[u*1024 + C], uint4 = f16 K-rows 8u..8u+7 of column C.
// C = 4*j + g; g: 0=i(Ul0,Wx0,b0) 1=o(Ul2,Wx2,b2) 2=f(Ul1,Wx2!,b1) 3=u(Ul3,Wx3,b3)
// rows r: <256 Ul (c-operand), <512 Ur (h-operand), <562 Wx (th), else 0
// ------------------------------------------------------------------
__global__ void pack_tree(const float* __restrict__ Ul, const float* __restrict__ Ur,
                          const float* __restrict__ Wx, uint4* __restrict__ PW) {
    int i = blockIdx.x * blockDim.x + threadIdx.x;
    if (i >= TREE_U * 1024) return;
    int u = i >> 10, C = i & 1023, j = C >> 2, g = C & 3;
    const int gl[4] = {0, 2, 1, 3};
    const int gx[4] = {0, 2, 2, 3};
    float f[8];
    for (int kk = 0; kk < 8; ++kk) {
        int r = u * 8 + kk;
        if (r < 256)      f[kk] = Ul[(gl[g] * H_ + j) * H_ + r];
        else if (r < 512) f[kk] = Ur[(gl[g] * H_ + j) * H_ + (r - 256)];
        else if (r < 562) f[kk] = Wx[(gx[g] * H_ + j) * D_ + (r - 512)];
        else              f[kk] = 0.0f;
    }
    PW[i] = make_uint4(packh2(f[0], f[1]), packh2(f[2], f[3]),
                       packh2(f[4], f[5]), packh2(f[6], f[7]));
}

// Tracking weights -> WTK[u*1000 + d*5 + ks], uint4 = f16 K-rows ks*168+8u .. +7 of dim d.
__global__ void pack_trk(const float* __restrict__ Wih, const float* __restrict__ Whh,
                         uint4* __restrict__ WT) {
    int i = blockIdx.x * blockDim.x + threadIdx.x;
    if (i >= TRK_U * 1000) return;
    int u = i / 1000, rem = i % 1000, d = rem / 5, ks = rem % 5;
    float f[8];
    for (int kk = 0; kk < 8; ++kk) {
        int r = ks * 168 + u * 8 + kk;
        if (r < 768)      f[kk] = Wih[d * 768 + r];
        else if (r < 818) f[kk] = Whh[d * 50 + (r - 768)];
        else              f[kk] = 0.0f;
    }
    WT[i] = make_uint4(packh2(f[0], f[1]), packh2(f[2], f[3]),
                       packh2(f[4], f[5]), packh2(f[6], f[7]));
}

__global__ void pack_bias(const float* __restrict__ bias4, const float* __restrict__ bih,
                          const float* __restrict__ bhh,
                          float* __restrict__ bcol, float* __restrict__ btrk) {
    int i = blockIdx.x * blockDim.x + threadIdx.x;
    if (i < 1024) {
        int j = i >> 2, g = i & 3;
        const int gb[4] = {0, 2, 1, 3};
        bcol[i] = bias4[gb[g] * H_ + j];
    } else if (i < 1224) {
        int d = i - 1024;
        btrk[d] = bih[d] + bhh[d];
    }
}

// zero flags + stack row 0 (ws is re-poisoned 0xAA before every timed launch)
__global__ void init_zero(float* __restrict__ ws) {
    int i = blockIdx.x * blockDim.x + threadIdx.x;
    if (i < B_ * T_ * 2) ((int*)(ws + OFF_FLAG))[i] = 0;
    if (i < B_ * H_) {
        int b = i >> 8, j = i & 255;
        ws[OFF_SH + (size_t)b * (T_ + 1) * H_ + j] = 0.0f;
        ws[OFF_SC + (size_t)b * (T_ + 1) * H_ + j] = 0.0f;
    }
}

// batched tree dot: issue S coalesced uint4 loads, then consume (8 dot2 each)
template <int S>
__device__ __forceinline__ void tree_batch(const uint4* __restrict__ wpk, int u0,
                                           const unsigned* __restrict__ q1,
                                           const unsigned* __restrict__ q2,
                                           float& a1, float& a2) {
    uint4 wb[S];
#pragma unroll
    for (int i = 0; i < S; ++i) wb[i] = wpk[(size_t)(u0 + i) << 10];
#pragma unroll
    for (int i = 0; i < S; ++i) {
        const int u = u0 + i;
        const uint4 v1 = *(const uint4*)(q1 + u * 4);
        const uint4 v2 = *(const uint4*)(q2 + u * 4);
        a1 = dot2(wb[i].x, v1.x, a1); a1 = dot2(wb[i].y, v1.y, a1);
        a1 = dot2(wb[i].z, v1.z, a1); a1 = dot2(wb[i].w, v1.w, a1);
        a2 = dot2(wb[i].x, v2.x, a2); a2 = dot2(wb[i].y, v2.y, a2);
        a2 = dot2(wb[i].z, v2.z, a2); a2 = dot2(wb[i].w, v2.w, a2);
    }
}

// ------------------------------------------------------------------
// Main: 256 WGs = 2 per batch element (column-split pair), 1024 threads.
// All weights streamed from L2 every step (tree 590KB + trk 336KB per WG);
// no persistent register arrays -> fits the 64-VGPR allocation the compiler
// picks for 1024-thread blocks, zero scratch.
// ------------------------------------------------------------------
__global__ __launch_bounds__(1024)
void trnn_main(const float* __restrict__ tokens_h, const float* __restrict__ tokens_c,
               const int* __restrict__ trans,
               const float* __restrict__ th0, const float* __restrict__ tc0,
               float* __restrict__ ws, const int* __restrict__ idx,
               float* __restrict__ out) {
    const int b   = blockIdx.x & 127;
    const int hw  = blockIdx.x >> 7;
    const int tid = threadIdx.x;

    float* stack_h = ws + OFF_SH + (size_t)b * (T_ + 1) * H_;
    float* stack_c = ws + OFF_SC + (size_t)b * (T_ + 1) * H_;
    const uint4* PWK4 = (const uint4*)(ws + OFF_PWK);
    const uint4* WTK4 = (const uint4*)(ws + OFF_WTK);
    const float* bcol = ws + OFF_BCOL;
    const float* btrk = ws + OFF_BTRK;
    int* flags = (int*)(ws + OFF_FLAG);

    __shared__ __align__(16) unsigned av1[288], av2[288];  // half2: [c|h|th|pad]
    __shared__ __align__(16) unsigned tav[420];            // half2: [bt_h|h1|h2|th|pad]
    __shared__ float h1s[256], h2s[256], c2s[256], bths[256], btcs[256];
    __shared__ float tc_l[50];
    __shared__ float ptrk[5][200];
    __shared__ float ptree[2][2][512];
    __shared__ float act[2][512];

    // tracking-thread invariants
    const int td  = tid / 5;     // output dim (0..199) for tid<1000
    const int tks = tid % 5;     // K-slice
    const bool trkA = tid < 1000;

    // tree invariants: thread = (col 0..511, khalf)
    const int col = tid & 511;
    const int kh  = tid >> 9;
    const uint4* wpk = PWK4 + (hw * 512 + col);
    const float bias_c = bcol[hw * 512 + col];

    // ---- init ----
    if (tid < 25) {
        float x = th0[b * D_ + 2 * tid], y = th0[b * D_ + 2 * tid + 1];
        unsigned p = packh2(x, y);
        av1[256 + tid] = p; av2[256 + tid] = p; tav[384 + tid] = p;
    }
    if (tid < 50) tc_l[tid] = tc0[b * D_ + tid];
    if (tid >= 281 && tid < 288) { av1[tid] = 0u; av2[tid] = 0u; }
    if (tid < 11) tav[409 + tid] = 0u;
    __syncthreads();

    for (int t = 1; t <= T_; ++t) {
        const int st = t - 1;
        const int i3 = (b * T_ + st) * 3;
        const int sp1 = idx[i3], sp2 = idx[i3 + 1], bp = idx[i3 + 2];

        // ---- P0: wait for partner's row t-1 ----
        if (t >= 2) {
            if (tid == 0) {
                int* f = &flags[(b * T_ + (t - 1)) * 2 + (hw ^ 1)];
                while (__hip_atomic_load(f, __ATOMIC_RELAXED, __HIP_MEMORY_SCOPE_AGENT) == 0)
                    __builtin_amdgcn_s_sleep(1);
            }
            __syncthreads();
        }

        // ---- P1: gather rows, convert to half2, keep f32 where combine needs ----
        {
            const int g = tid >> 7, t2 = tid & 127;
            const int e0 = 2 * t2, e1 = e0 + 1;
            if (g == 0) {
                float x = aload(&stack_c[sp1 * H_ + e0]), y = aload(&stack_c[sp1 * H_ + e1]);
                av1[t2] = packh2(x, y);
            } else if (g == 1) {
                float x = aload(&stack_h[sp1 * H_ + e0]), y = aload(&stack_h[sp1 * H_ + e1]);
                unsigned p = packh2(x, y);
                av1[128 + t2] = p; tav[128 + t2] = p; h1s[e0] = x; h1s[e1] = y;
            } else if (g == 2) {
                float x = aload(&stack_c[sp2 * H_ + e0]), y = aload(&stack_c[sp2 * H_ + e1]);
                av2[t2] = packh2(x, y); c2s[e0] = x; c2s[e1] = y;
            } else if (g == 3) {
                float x = aload(&stack_h[sp2 * H_ + e0]), y = aload(&stack_h[sp2 * H_ + e1]);
                unsigned p = packh2(x, y);
                av2[128 + t2] = p; tav[256 + t2] = p; h2s[e0] = x; h2s[e1] = y;
            } else if (g == 4) {
                const float* src = tokens_h + ((size_t)b * N_ + bp) * H_;
                float x = src[e0], y = src[e1];
                tav[t2] = packh2(x, y); bths[e0] = x; bths[e1] = y;
            } else if (g == 5) {
                const float* src = tokens_c + ((size_t)b * N_ + bp) * H_;
                btcs[e0] = src[e0]; btcs[e1] = src[e1];
            }
        }
        __syncthreads();

        // ---- P2: tracking partials (21 uint4 streamed as 3 batches of 7) ----
        if (trkA) {
            const unsigned* tv = tav + tks * 84;
            float a = 0.f;
#pragma unroll
            for (int bt = 0; bt < 3; ++bt) {
                uint4 sb[7];
#pragma unroll
                for (int i = 0; i < 7; ++i)
                    sb[i] = WTK4[(bt * 7 + i) * 1000 + tid];
#pragma unroll
                for (int i = 0; i < 7; ++i) {
                    const uint4 v = *(const uint4*)(tv + (bt * 7 + i) * 4);
                    a = dot2(sb[i].x, v.x, a); a = dot2(sb[i].y, v.y, a);
                    a = dot2(sb[i].z, v.z, a); a = dot2(sb[i].w, v.w, a);
                }
            }
            ptrk[tks][td] = a;
        }
        __syncthreads();

        // ---- P3 (threads 0..24): th/tc update; others fall straight into tree ----
        if (tid < 25) {
            float thv0 = 0.f, thv1 = 0.f;
#pragma unroll
            for (int q = 0; q < 2; ++q) {
                const int d = 2 * tid + q;
                float gi = btrk[d], gf = btrk[50 + d], gg = btrk[100 + d], go = btrk[150 + d];
#pragma unroll
                for (int ks = 0; ks < 5; ++ks) {
                    gi += ptrk[ks][d]; gf += ptrk[ks][50 + d];
                    gg += ptrk[ks][100 + d]; go += ptrk[ks][150 + d];
                }
                float c = fmaf(sigf(gf), tc_l[d], sigf(gi) * tanhf(gg));
                tc_l[d] = c;
                float thv = sigf(go) * tanhf(c);
                if (q == 0) thv0 = thv; else thv1 = thv;
            }
            unsigned p = packh2(thv0, thv1);
            av1[256 + tid] = p; av2[256 + tid] = p; tav[384 + tid] = p;
        }

        // ---- tree main (rows 0..511: no th dependency; overlaps P3) ----
        float a1 = 0.f, a2 = 0.f;
        if (kh == 0) {
            tree_batch<6>(wpk, 0,  av1, av2, a1, a2);
            tree_batch<6>(wpk, 6,  av1, av2, a1, a2);
            tree_batch<6>(wpk, 12, av1, av2, a1, a2);
            tree_batch<6>(wpk, 18, av1, av2, a1, a2);
            tree_batch<6>(wpk, 24, av1, av2, a1, a2);
            tree_batch<6>(wpk, 30, av1, av2, a1, a2);
            ptree[0][0][col] = a1; ptree[1][0][col] = a2;
        } else {
            tree_batch<7>(wpk, 36, av1, av2, a1, a2);
            tree_batch<7>(wpk, 43, av1, av2, a1, a2);
            tree_batch<7>(wpk, 50, av1, av2, a1, a2);
            tree_batch<7>(wpk, 57, av1, av2, a1, a2);
        }
        __syncthreads();   // th (P3) now visible

        // ---- tree tail (rows 512..575: th block) ----
        if (kh == 1) {
            tree_batch<4>(wpk, 64, av1, av2, a1, a2);
            tree_batch<4>(wpk, 68, av1, av2, a1, a2);
            ptree[0][1][col] = a1; ptree[1][1][col] = a2;
        }
        __syncthreads();

        // ---- P5: reduce + nonlinearity (thread = (call, col)) ----
        {
            const int call = tid >> 9, c = tid & 511;
            float s = bias_c + ptree[call][0][c] + ptree[call][1][c];
            act[call][c] = ((c & 3) == 3) ? tanhf(s) : sigf(s);
        }
        __syncthreads();

        // ---- P6: combine + stack write (our 128 of 256 output rows) ----
        if (tid < 128) {
            const int jl = tid, j = hw * 128 + jl;
            const int c0 = 4 * jl;
            const float i1 = act[0][c0], o1 = act[0][c0 + 1], f1 = act[0][c0 + 2], u1 = act[0][c0 + 3];
            const float i2 = act[1][c0], o2 = act[1][c0 + 1], f2 = act[1][c0 + 2], u2 = act[1][c0 + 3];
            // faithful to source: cc1 = i*u + f*(c2+h2); cc2 = i*u + f*(c2+h1)
            const float cc1 = fmaf(i1, u1, f1 * (c2s[j] + h2s[j]));
            const float cc2 = fmaf(i2, u2, f2 * (c2s[j] + h1s[j]));
            const float hh1 = o1 * tanhf(cc1);
            const float hh2 = o2 * tanhf(cc2);
            const int tr = trans[b * T_ + st];
            float nh, nc;
            if (tr == 0)      { nh = bths[j]; nc = btcs[j]; }
            else if (tr == 1) { nh = hh1; nc = cc1; }
            else              { nh = hh2; nc = cc2; }
            astore(&stack_h[t * H_ + j], nh);
            astore(&stack_c[t * H_ + j], nc);
            if (t == T_) out[b * H_ + j] = nh;
        }
        asm volatile("s_waitcnt vmcnt(0)" ::: "memory");
        __syncthreads();
        if (tid == 0 && t < T_) {
            __hip_atomic_store(&flags[(b * T_ + t) * 2 + hw], 1,
                               __ATOMIC_RELEASE, __HIP_MEMORY_SCOPE_AGENT);
        }
    }
}

extern "C" void kernel_launch(void* const* d_in, const int* in_sizes, int n_in,
                              void* d_out, int out_size, void* d_ws, size_t ws_size,
                              hipStream_t stream) {
    (void)in_sizes; (void)n_in; (void)out_size; (void)ws_size;
    const float* tokens_h = (const float*)d_in[0];
    const float* tokens_c = (const float*)d_in[1];
    const int*   trans    = (const int*)d_in[2];
    const float* th0      = (const float*)d_in[3];
    const float* tc0      = (const float*)d_in[4];
    const float* Wx       = (const float*)d_in[5];
    const float* Ul       = (const float*)d_in[6];
    const float* Ur       = (const float*)d_in[7];
    const float* bias4    = (const float*)d_in[8];
    const float* Wih      = (const float*)d_in[9];
    const float* Whh      = (const float*)d_in[10];
    const float* bih      = (const float*)d_in[11];
    const float* bhh      = (const float*)d_in[12];

    float* ws = (float*)d_ws;
    uint4* PWK  = (uint4*)(ws + OFF_PWK);
    uint4* WTK  = (uint4*)(ws + OFF_WTK);
    float* bcol = ws + OFF_BCOL;
    float* btrk = ws + OFF_BTRK;
    int*   idx  = (int*)(ws + OFF_IDX);

    hipLaunchKernelGGL(init_zero, dim3(256), dim3(256), 0, stream, ws);
    hipLaunchKernelGGL(sim_idx, dim3(1), dim3(128), 0, stream, trans, idx);
    hipLaunchKernelGGL(pack_tree, dim3((TREE_U * 1024 + 255) / 256), dim3(256), 0, stream,
                       Ul, Ur, Wx, PWK);
    hipLaunchKernelGGL(pack_trk, dim3((TRK_U * 1000 + 255) / 256), dim3(256), 0, stream,
                       Wih, Whh, WTK);
    hipLaunchKernelGGL(pack_bias, dim3(5), dim3(256), 0, stream, bias4, bih, bhh, bcol, btrk);
    hipLaunchKernelGGL(trnn_main, dim3(256), dim3(1024), 0, stream,
                       tokens_h, tokens_c, trans, th0, tc0, ws, idx, (float*)d_out);
}